// Round 8
// baseline (174.799 us; speedup 1.0000x reference)
//
#include <hip/hip_runtime.h>
#include <hip/hip_bf16.h>
#include <math.h>

// Problem constants
#define HID   64
#define VOCABN 64
#define INNER 24
#define SEQN  32
#define CAPN  8
#define NPOS  17
#define BATCHN 8192

typedef float f32x4 __attribute__((ext_vector_type(4)));
typedef float f32x2 __attribute__((ext_vector_type(2)));
typedef int   i32x2 __attribute__((ext_vector_type(2)));

// f32x4 helpers. (r2 lesson: packing saves issue slots only, not fp32 ALU
// cycles, on gfx950 — vectors are for register pairing and code clarity.)
static __device__ __forceinline__ f32x4 sp4(float x) { return (f32x4){x, x, x, x}; }
static __device__ __forceinline__ f32x4 fma4(f32x4 a, f32x4 b, f32x4 c) {
  f32x4 r; r.x = fmaf(a.x, b.x, c.x); r.y = fmaf(a.y, b.y, c.y);
           r.z = fmaf(a.z, b.z, c.z); r.w = fmaf(a.w, b.w, c.w); return r;
}
static __device__ __forceinline__ f32x4 max4(f32x4 a, float b) {
  f32x4 r; r.x = fmaxf(a.x, b); r.y = fmaxf(a.y, b);
           r.z = fmaxf(a.z, b); r.w = fmaxf(a.w, b); return r;
}
static __device__ __forceinline__ f32x4 rsq4(f32x4 a) {
  f32x4 r; r.x = __builtin_amdgcn_rsqf(a.x); r.y = __builtin_amdgcn_rsqf(a.y);
           r.z = __builtin_amdgcn_rsqf(a.z); r.w = __builtin_amdgcn_rsqf(a.w); return r;
}

// Per-step Adam prefactor (double-precision offline):
//   cmsbr[t] = LR * sqrt(1 - B2^(t+1)) / (1 - B1^(t+1)),  t = 0..7
static __device__ const float CMSBR[8] = {
  0.01581139f, 0.01176584f, 0.01010053f, 0.00918844f,
  0.00862495f, 0.00825540f, 0.00800653f, 0.00783856f
};

// ds_swizzle pattern must be an integer-constant-expression at the builtin
// call site (r4 compile failure) -> template parameter.
template <int PAT>
static __device__ __forceinline__ float swz(float x) {
  return __int_as_float(__builtin_amdgcn_ds_swizzle(__float_as_int(x), PAT));
}

// permlane{16,32}_swap butterfly-add on the VALU pipe (gfx950-new; no DS, no
// lgkmcnt). r7 POST-MORTEM: hand-rolled asm (v_mov + swap in one asm block)
// read a stale operand — gfx950 has a VALU-write -> permlane-read hazard the
// compiler fences only for instructions it emits itself. Use the BUILTINS:
// they return both results {vdst', src'}; with both inputs = x, the pair is
// (own, partner) or (partner, own) per lane — fp add is bitwise-commutative,
// so r.x + r.y is the bit-exact xor16/xor32 butterfly stage either way.
#if defined(__has_builtin)
#  if __has_builtin(__builtin_amdgcn_permlane16_swap)
#    define HAVE_PL16 1
#  endif
#  if __has_builtin(__builtin_amdgcn_permlane32_swap)
#    define HAVE_PL32 1
#  endif
#endif

static __device__ __forceinline__ float bflyP16(float x) {   // lane^16
#ifdef HAVE_PL16
  i32x2 r = __builtin_amdgcn_permlane16_swap(__float_as_int(x),
                                             __float_as_int(x), false, false);
  return __int_as_float(r.x) + __int_as_float(r.y);
#else
  return x + swz<0x401F>(x);          // DS fallback (r6-class perf)
#endif
}
static __device__ __forceinline__ float bflyP32(float x) {   // lane^32
#ifdef HAVE_PL32
  i32x2 r = __builtin_amdgcn_permlane32_swap(__float_as_int(x),
                                             __float_as_int(x), false, false);
  return __int_as_float(r.x) + __int_as_float(r.y);
#else
  return x + __shfl_xor(x, 32);       // DS fallback
#endif
}

// ---------- quad all-reduce: 64 leaves j = 4*u16 + slot ----------
// Lane remap (r7): u16 = lane bits {0,1,4,5}, g = lane bits {2,3}. Stages
// combine j-bits in ascending order (bit-exact lineage tree):
//   bits 0,1 in-register; bit2 = lane^1 (DPP); bit3 = lane^2 (DPP);
//   bit4 = lane^16 (permlane16_swap); bit5 = lane^32 (permlane32_swap).
// ZERO DS ops per reduce (was 2).
__device__ __forceinline__ float allred16q(f32x4 p) {
  float x = (p.x + p.y) + (p.z + p.w);   // j-bits 0,1
  int y;
  y = __builtin_amdgcn_update_dpp(__float_as_int(x), __float_as_int(x),
                                  0xB1, 0xF, 0xF, false);   // lane^1 -> j-bit2
  x += __int_as_float(y);
  y = __builtin_amdgcn_update_dpp(__float_as_int(x), __float_as_int(x),
                                  0x4E, 0xF, 0xF, false);   // lane^2 -> j-bit3
  x += __int_as_float(y);
  x = bflyP16(x);                                           // lane^16 -> j-bit4
  x = bflyP32(x);                                           // lane^32 -> j-bit5
  return x;
}

// ---------- Kernel 1: per-token encoder table (verbatim, passing) ----------
__global__ __launch_bounds__(128) void build_table(
    const float* __restrict__ embed,    // [64][64]
    const float* __restrict__ ff_w1,    // [64][128]
    const float* __restrict__ ff_b1,    // [128]
    const float* __restrict__ ff_w2,    // [128][64]
    const float* __restrict__ ff_b2,    // [64]
    const float* __restrict__ ln_g,     // [64]
    const float* __restrict__ ln_b,     // [64]
    float* __restrict__ etab)           // [64][64]
{
  __shared__ float h[64];
  __shared__ float A1[128];
  __shared__ float xs[64];
  const int r = blockIdx.x;
  const int t = threadIdx.x;

  if (t < 64) h[t] = embed[r * 64 + t];
  __syncthreads();

  {
    float acc = ff_b1[t];
    #pragma unroll 8
    for (int k = 0; k < 64; ++k)
      acc = fmaf(h[k], ff_w1[k * 128 + t], acc);
    A1[t] = fmaxf(acc, 0.f);
  }
  __syncthreads();

  if (t < 64) {
    float acc = ff_b2[t];
    #pragma unroll 8
    for (int k = 0; k < 128; ++k)
      acc = fmaf(A1[k], ff_w2[k * 64 + t], acc);
    xs[t] = acc + h[t];
  }
  __syncthreads();

  if (t < 64) {
    float s1 = 0.f;
    if (t < 4)
      for (int j = 0; j < 16; ++j) s1 += xs[t + 4 * j];
    s1 += __shfl_xor(s1, 1);
    s1 += __shfl_xor(s1, 2);
    s1 = __shfl(s1, 0);
    float mu = s1 * 0.015625f;

    float s2 = 0.f;
    if (t < 4)
      for (int j = 0; j < 16; ++j) {
        float d = xs[t + 4 * j] - mu;
        s2 = fmaf(d, d, s2);
      }
    s2 += __shfl_xor(s2, 1);
    s2 += __shfl_xor(s2, 2);
    s2 = __shfl(s2, 0);
    float var = s2 * 0.015625f;
    float rs  = rsqrtf(var + 1e-5f);

    etab[r * 64 + t] = fmaf((xs[t] - mu) * rs, ln_g[t], ln_b[t]);
  }
}

// ---------- Kernel 2: 1-wave-per-sample, quad layout, 8-step Adam ----------
// Bit-exact per component with the r9-lineage scalar adam_upd.
__device__ __forceinline__ void adam_q(f32x4& p, f32x4& m, f32x4& v,
                                       f32x4 g1, f32x4 g2, float cmsbr) {
  m = fma4(sp4(0.9f),   m, g1);
  v = fma4(sp4(0.999f), v, g2);
  f32x4 r = rsq4(max4(v, 1e-30f));
  f32x4 t = m * sp4(cmsbr);
  p = fma4(-t, r, p);
}

// Layout: one wave per sample. u16 = (lane&3)|((lane>>2)&12) (lane bits
// 0,1,4,5) owns the j/c quad {4u16..4u16+3}; g = (lane>>2)&3 (lane bits 2,3)
// owns inner dims 6g..6g+5. Reduces run entirely on DPP+permlane (VALU);
// only the y cross-group combine (g-bits -> xor4, xor8) uses ds_swizzle:
// 8 DS/step total (was 32). Ownership/bias formulas in u16/g terms carry
// over verbatim from r5/r6 — bit-exact lineage.
__global__ __launch_bounds__(256, 2) void adapt_kernel(
    const int* __restrict__ seqs,       // [BATCH][32]
    const float* __restrict__ etab,     // [64][64]
    const float* __restrict__ mlp_w1,   // [64][24]
    const float* __restrict__ mlp_b1,   // [24]
    const float* __restrict__ mlp_w2,   // [24][64]
    const float* __restrict__ mlp_b2,   // [64]
    const float* __restrict__ out_w,    // [64][64]
    const float* __restrict__ out_b,    // [64]
    float* __restrict__ out)            // [BATCH][64]
{
  __shared__ __align__(16) float hqv[4][64];
  const int t    = threadIdx.x;        // 0..255
  const int wv   = t >> 6;             // wave in block = sample slot
  const int lane = t & 63;
  const int u16  = (lane & 3) | ((lane >> 2) & 12);  // lane bits 0,1,4,5
  const int g    = (lane >> 2) & 3;                  // lane bits 2,3
  const int s    = blockIdx.x * 4 + wv;
  const int off  = 6 * g;              // first inner dim of this group's 6

  // Tokens are wave-uniform: uniform (scalar) loads.
  const int* __restrict__ srow = seqs + s * SEQN + 14;

  // state: lane owns w1[4u16+sl][off+m] and w2[off+m][4u16+sl], sl=0..3
  f32x4 w1q[6], m1q[6], v1q[6], w2q[6], m2q[6], v2q[6];
  #pragma unroll
  for (int m = 0; m < 6; ++m) {
    f32x4 a;
    a.x = mlp_w1[(4 * u16 + 0) * INNER + off + m];
    a.y = mlp_w1[(4 * u16 + 1) * INNER + off + m];
    a.z = mlp_w1[(4 * u16 + 2) * INNER + off + m];
    a.w = mlp_w1[(4 * u16 + 3) * INNER + off + m];
    w1q[m] = a;
    w2q[m] = *(const f32x4*)&mlp_w2[(off + m) * HID + 4 * u16];
    m1q[m] = sp4(0.f); v1q[m] = sp4(0.f); m2q[m] = sp4(0.f); v2q[m] = sp4(0.f);
  }
  // b1: owner == injector lane. Bias for dim i=6g+m sits at leaf j = i mod 12
  // = 6*(g&1)+m -> lane u16 = j>>2, slot j&3 (same formulas as r5/r6).
  f32x4 b1q = sp4(0.f);
  if (!(g & 1)) {
    if (u16 == 0) { b1q.x = mlp_b1[off + 0]; b1q.y = mlp_b1[off + 1];
                    b1q.z = mlp_b1[off + 2]; b1q.w = mlp_b1[off + 3]; }
    else if (u16 == 1) { b1q.x = mlp_b1[off + 4]; b1q.y = mlp_b1[off + 5]; }
  } else {
    if (u16 == 1) { b1q.z = mlp_b1[off + 0]; b1q.w = mlp_b1[off + 1]; }
    else if (u16 == 2) { b1q.x = mlp_b1[off + 2]; b1q.y = mlp_b1[off + 3];
                         b1q.z = mlp_b1[off + 4]; b1q.w = mlp_b1[off + 5]; }
  }
  f32x4 mb1 = sp4(0.f), vb1 = sp4(0.f);
  // b2: every lane maintains b2[4u16..4u16+3] redundantly (same bits in all
  // groups). Seeded into the y chain only in group 0.
  f32x4 b2q = *(const f32x4*)&mlp_b2[4 * u16];
  f32x4 mb2 = sp4(0.f), vb2 = sp4(0.f);

  const bool ge0 = !(g & 1) && (u16 == 0);
  const bool ge1 = !(g & 1) && (u16 == 1);
  const bool go1 =  (g & 1) && (u16 == 1);
  const bool go2 =  (g & 1) && (u16 == 2);
  const bool g0a = (g == 0);

  // first k,v rows, quad layout (dwordx4 from L1/L2-resident etab; the wave
  // still covers all 16 chunks of the row — lane order is just permuted)
  const f32x4* e4 = (const f32x4*)etab;
  f32x4 kp = e4[srow[0] * 16 + u16];
  f32x4 vp = e4[srow[1] * 16 + u16];

  #pragma unroll 2
  for (int st = 0; st < 8; ++st) {
    const float cmsbr = CMSBR[st];

    // forward: z_i = allred(k_j * w1[j][i]) + b1 at leaf (i mod 12).
    f32x4 pz[6];
    #pragma unroll
    for (int m = 0; m < 6; ++m) pz[m] = kp * w1q[m];
    pz[0].x += ge0 ? b1q.x : 0.f;  pz[0].z += go1 ? b1q.z : 0.f;
    pz[1].y += ge0 ? b1q.y : 0.f;  pz[1].w += go1 ? b1q.w : 0.f;
    pz[2].z += ge0 ? b1q.z : 0.f;  pz[2].x += go2 ? b1q.x : 0.f;
    pz[3].w += ge0 ? b1q.w : 0.f;  pz[3].y += go2 ? b1q.y : 0.f;
    pz[4].x += ge1 ? b1q.x : 0.f;  pz[4].z += go2 ? b1q.z : 0.f;
    pz[5].y += ge1 ? b1q.y : 0.f;  pz[5].w += go2 ? b1q.w : 0.f;
    float a_[6];
    #pragma unroll
    for (int m = 0; m < 6; ++m) a_[m] = allred16q(pz[m]);
    #pragma unroll
    for (int m = 0; m < 6; ++m) a_[m] = fmaxf(a_[m], 0.f);

    // y chain over this group's 6 dims (seeded b2 in group 0 only)
    f32x4 yq;
    yq.x = g0a ? b2q.x : 0.f; yq.y = g0a ? b2q.y : 0.f;
    yq.z = g0a ? b2q.z : 0.f; yq.w = g0a ? b2q.w : 0.f;
    #pragma unroll
    for (int m = 0; m < 6; ++m) yq = fma4(sp4(a_[m]), w2q[m], yq);
    // combine: g-bit0 = lane^4 (swz), g-bit1 = lane^8 (swz) — same
    // (c0+c1)+(c2+c3) lineage tree, new physical stages.
    { f32x4 e; e.x = swz<0x101F>(yq.x); e.y = swz<0x101F>(yq.y);
               e.z = swz<0x101F>(yq.z); e.w = swz<0x101F>(yq.w);
      yq = yq + e; }
    { f32x4 e; e.x = swz<0x201F>(yq.x); e.y = swz<0x201F>(yq.y);
               e.z = swz<0x201F>(yq.z); e.w = swz<0x201F>(yq.w);
      yq = yq + e; }
    f32x4 dyq = (yq - vp) * sp4(0.03125f);   // 2/64

    // prefetch next step's k,v (st=7 harmlessly loads q row twice)
    int pp1 = 2 * st + 2; pp1 = pp1 < 16 ? pp1 : 16;
    int pp2 = 2 * st + 3; pp2 = pp2 < 16 ? pp2 : 16;
    f32x4 kn = e4[srow[pp1] * 16 + u16];
    f32x4 vn = e4[srow[pp2] * 16 + u16];

    // backward: dz_i = (z_i>0) * allred(w2[i][c]*dy_c)
    float dz[6];
    #pragma unroll
    for (int m = 0; m < 6; ++m) dz[m] = allred16q(w2q[m] * dyq);
    #pragma unroll
    for (int m = 0; m < 6; ++m) dz[m] = (a_[m] > 0.f) ? dz[m] : 0.f;

    // Adam step st+1 — w1/b1 first (gate next forward), then w2/b2
    // (unroll-2 lets the scheduler overlap these with the next forward).
    f32x4 k01  = kp * sp4(0.1f);
    f32x4 ksq  = (sp4(0.001f) * kp) * kp;
    f32x4 dy01 = dyq * sp4(0.1f);
    f32x4 dysq = (sp4(0.001f) * dyq) * dyq;
    #pragma unroll
    for (int m = 0; m < 6; ++m) {
      float dzs = dz[m] * dz[m];
      adam_q(w1q[m], m1q[m], v1q[m], k01 * sp4(dz[m]), ksq * sp4(dzs), cmsbr);
    }
    // b1 grads: owner slots gather their dz; non-owner slots get garbage that
    // is never read (lineage-sanctioned)
    {
      float gg0 = ge0 ? dz[0] : ge1 ? dz[4] : dz[2];
      float gg1 = ge0 ? dz[1] : ge1 ? dz[5] : dz[3];
      float gg2 = go1 ? dz[0] : ge0 ? dz[2] : dz[4];
      float gg3 = go1 ? dz[1] : ge0 ? dz[3] : dz[5];
      f32x4 g1b; g1b.x = 0.1f * gg0; g1b.y = 0.1f * gg1;
                 g1b.z = 0.1f * gg2; g1b.w = 0.1f * gg3;
      f32x4 g2b; g2b.x = 0.001f * (gg0 * gg0); g2b.y = 0.001f * (gg1 * gg1);
                 g2b.z = 0.001f * (gg2 * gg2); g2b.w = 0.001f * (gg3 * gg3);
      adam_q(b1q, mb1, vb1, g1b, g2b, cmsbr);
    }
    #pragma unroll
    for (int m = 0; m < 6; ++m) {
      float as = a_[m] * a_[m];
      adam_q(w2q[m], m2q[m], v2q[m], dy01 * sp4(a_[m]), dysq * sp4(as), cmsbr);
    }
    // b2: all lanes, redundant across groups (identical bits)
    adam_q(b2q, mb2, vb2, dy01, dysq, cmsbr);

    kp = kn; vp = vn;
  }

  // final forward with q (kp holds q row after last prefetch)
  {
    f32x4 pz[6];
    #pragma unroll
    for (int m = 0; m < 6; ++m) pz[m] = kp * w1q[m];
    pz[0].x += ge0 ? b1q.x : 0.f;  pz[0].z += go1 ? b1q.z : 0.f;
    pz[1].y += ge0 ? b1q.y : 0.f;  pz[1].w += go1 ? b1q.w : 0.f;
    pz[2].z += ge0 ? b1q.z : 0.f;  pz[2].x += go2 ? b1q.x : 0.f;
    pz[3].w += ge0 ? b1q.w : 0.f;  pz[3].y += go2 ? b1q.y : 0.f;
    pz[4].x += ge1 ? b1q.x : 0.f;  pz[4].z += go2 ? b1q.z : 0.f;
    pz[5].y += ge1 ? b1q.y : 0.f;  pz[5].w += go2 ? b1q.w : 0.f;
    float aq[6];
    #pragma unroll
    for (int m = 0; m < 6; ++m) aq[m] = fmaxf(allred16q(pz[m]), 0.f);
    f32x4 hq;
    hq.x = g0a ? b2q.x : 0.f; hq.y = g0a ? b2q.y : 0.f;
    hq.z = g0a ? b2q.z : 0.f; hq.w = g0a ? b2q.w : 0.f;
    #pragma unroll
    for (int m = 0; m < 6; ++m) hq = fma4(sp4(aq[m]), w2q[m], hq);
    { f32x4 e; e.x = swz<0x101F>(hq.x); e.y = swz<0x101F>(hq.y);
               e.z = swz<0x101F>(hq.z); e.w = swz<0x101F>(hq.w);
      hq = hq + e; }
    { f32x4 e; e.x = swz<0x201F>(hq.x); e.y = swz<0x201F>(hq.y);
               e.z = swz<0x201F>(hq.z); e.w = swz<0x201F>(hq.w);
      hq = hq + e; }
    if (g0a) ((f32x4*)hqv[wv])[u16] = hq;   // hqv[wv][4u16+sl] = hq_j
  }
  __syncthreads();   // once per kernel: publish hqv

  {
    // out[s][c] = sum_j hq[j] * out_w[j][c] + out_b[c]   (lane = c, all 64)
    float acc = out_b[lane];
    const f32x4* hv = (const f32x4*)hqv[wv];
    #pragma unroll
    for (int j4 = 0; j4 < 16; ++j4) {
      f32x4 h4 = hv[j4];
      acc = fmaf(h4.x, out_w[(4 * j4 + 0) * 64 + lane], acc);
      acc = fmaf(h4.y, out_w[(4 * j4 + 1) * 64 + lane], acc);
      acc = fmaf(h4.z, out_w[(4 * j4 + 2) * 64 + lane], acc);
      acc = fmaf(h4.w, out_w[(4 * j4 + 3) * 64 + lane], acc);
    }
    out[(size_t)s * 64 + lane] = acc;
  }
}

extern "C" void kernel_launch(void* const* d_in, const int* in_sizes, int n_in,
                              void* d_out, int out_size, void* d_ws, size_t ws_size,
                              hipStream_t stream) {
  const int*   seqs   = (const int*)d_in[0];
  const float* embed  = (const float*)d_in[1];
  const float* ff_w1  = (const float*)d_in[2];
  const float* ff_b1  = (const float*)d_in[3];
  const float* ff_w2  = (const float*)d_in[4];
  const float* ff_b2  = (const float*)d_in[5];
  const float* ln_g   = (const float*)d_in[6];
  const float* ln_b   = (const float*)d_in[7];
  const float* mlp_w1 = (const float*)d_in[8];
  const float* mlp_b1 = (const float*)d_in[9];
  const float* mlp_w2 = (const float*)d_in[10];
  const float* mlp_b2 = (const float*)d_in[11];
  const float* out_w  = (const float*)d_in[12];
  const float* out_b  = (const float*)d_in[13];

  float* etab = (float*)d_ws;   // 64*64 f32 = 16 KB

  build_table<<<64, 128, 0, stream>>>(
      embed, ff_w1, ff_b1, ff_w2, ff_b2, ln_g, ln_b, etab);
  adapt_kernel<<<BATCHN / 4, 256, 0, stream>>>(
      seqs, etab, mlp_w1, mlp_b1, mlp_w2, mlp_b2, out_w, out_b,
      (float*)d_out);
}

// Round 9
// 170.318 us; speedup vs baseline: 1.0263x; 1.0263x over previous
//
#include <hip/hip_runtime.h>
#include <hip/hip_bf16.h>
#include <math.h>

// Problem constants
#define HID   64
#define VOCABN 64
#define INNER 24
#define SEQN  32
#define CAPN  8
#define NPOS  17
#define BATCHN 8192

typedef float f32x4 __attribute__((ext_vector_type(4)));

// f32x4 helpers. (r2 lesson: packing saves issue slots only, not fp32 ALU
// cycles, on gfx950. r8 lesson: the kernel is VALU-THROUGHPUT-bound — DS ops
// are hidden/free, so keep butterfly stages on the DS pipe, not VALU.)
static __device__ __forceinline__ f32x4 sp4(float x) { return (f32x4){x, x, x, x}; }
static __device__ __forceinline__ f32x4 fma4(f32x4 a, f32x4 b, f32x4 c) {
  f32x4 r; r.x = fmaf(a.x, b.x, c.x); r.y = fmaf(a.y, b.y, c.y);
           r.z = fmaf(a.z, b.z, c.z); r.w = fmaf(a.w, b.w, c.w); return r;
}
static __device__ __forceinline__ f32x4 max4(f32x4 a, float b) {
  f32x4 r; r.x = fmaxf(a.x, b); r.y = fmaxf(a.y, b);
           r.z = fmaxf(a.z, b); r.w = fmaxf(a.w, b); return r;
}
static __device__ __forceinline__ f32x4 rsq4(f32x4 a) {
  f32x4 r; r.x = __builtin_amdgcn_rsqf(a.x); r.y = __builtin_amdgcn_rsqf(a.y);
           r.z = __builtin_amdgcn_rsqf(a.z); r.w = __builtin_amdgcn_rsqf(a.w); return r;
}

// Per-step Adam prefactor (double-precision offline):
//   cmsbr[t] = LR * sqrt(1 - B2^(t+1)) / (1 - B1^(t+1)),  t = 0..7
static __device__ const float CMSBR[8] = {
  0.01581139f, 0.01176584f, 0.01010053f, 0.00918844f,
  0.00862495f, 0.00825540f, 0.00800653f, 0.00783856f
};

// ds_swizzle pattern must be an integer-constant-expression at the builtin
// call site (r4 compile failure) -> template parameter.
template <int PAT>
static __device__ __forceinline__ float swz(float x) {
  return __int_as_float(__builtin_amdgcn_ds_swizzle(__float_as_int(x), PAT));
}

// ---------- quad all-reduce: 64 leaves j = 4*u16 + slot, u16 = lane&15 ----------
// Bit-exact lineage tree: bits 0,1 in-register; bit2 = lane^1 (DPP);
// bit3 = lane^2 (DPP); bit4 = lane^4 (swz); bit5 = lane^8 (swz).
// r8 lesson: these 2 DS ops/reduce are FREE (hidden); permlane (VALU) was
// 16 µs slower. This is the proven r6 form.
__device__ __forceinline__ float allred16q(f32x4 p) {
  float x = (p.x + p.y) + (p.z + p.w);   // j-bits 0,1
  int y;
  y = __builtin_amdgcn_update_dpp(__float_as_int(x), __float_as_int(x),
                                  0xB1, 0xF, 0xF, false);   // u16^1 -> j-bit2
  x += __int_as_float(y);
  y = __builtin_amdgcn_update_dpp(__float_as_int(x), __float_as_int(x),
                                  0x4E, 0xF, 0xF, false);   // u16^2 -> j-bit3
  x += __int_as_float(y);
  x += swz<0x101F>(x);                                      // u16^4 -> j-bit4
  x += swz<0x201F>(x);                                      // u16^8 -> j-bit5
  return x;
}

// ---------- Kernel 1: per-token encoder table (verbatim, passing) ----------
__global__ __launch_bounds__(128) void build_table(
    const float* __restrict__ embed,    // [64][64]
    const float* __restrict__ ff_w1,    // [64][128]
    const float* __restrict__ ff_b1,    // [128]
    const float* __restrict__ ff_w2,    // [128][64]
    const float* __restrict__ ff_b2,    // [64]
    const float* __restrict__ ln_g,     // [64]
    const float* __restrict__ ln_b,     // [64]
    float* __restrict__ etab)           // [64][64]
{
  __shared__ float h[64];
  __shared__ float A1[128];
  __shared__ float xs[64];
  const int r = blockIdx.x;
  const int t = threadIdx.x;

  if (t < 64) h[t] = embed[r * 64 + t];
  __syncthreads();

  {
    float acc = ff_b1[t];
    #pragma unroll 8
    for (int k = 0; k < 64; ++k)
      acc = fmaf(h[k], ff_w1[k * 128 + t], acc);
    A1[t] = fmaxf(acc, 0.f);
  }
  __syncthreads();

  if (t < 64) {
    float acc = ff_b2[t];
    #pragma unroll 8
    for (int k = 0; k < 128; ++k)
      acc = fmaf(A1[k], ff_w2[k * 64 + t], acc);
    xs[t] = acc + h[t];
  }
  __syncthreads();

  if (t < 64) {
    float s1 = 0.f;
    if (t < 4)
      for (int j = 0; j < 16; ++j) s1 += xs[t + 4 * j];
    s1 += __shfl_xor(s1, 1);
    s1 += __shfl_xor(s1, 2);
    s1 = __shfl(s1, 0);
    float mu = s1 * 0.015625f;

    float s2 = 0.f;
    if (t < 4)
      for (int j = 0; j < 16; ++j) {
        float d = xs[t + 4 * j] - mu;
        s2 = fmaf(d, d, s2);
      }
    s2 += __shfl_xor(s2, 1);
    s2 += __shfl_xor(s2, 2);
    s2 = __shfl(s2, 0);
    float var = s2 * 0.015625f;
    float rs  = rsqrtf(var + 1e-5f);

    etab[r * 64 + t] = fmaf((xs[t] - mu) * rs, ln_g[t], ln_b[t]);
  }
}

// ---------- Kernel 2: 1-wave-per-sample, quad layout, 8-step Adam ----------
// Bit-exact per component with the r9-lineage scalar adam_upd.
__device__ __forceinline__ void adam_q(f32x4& p, f32x4& m, f32x4& v,
                                       f32x4 g1, f32x4 g2, float cmsbr) {
  m = fma4(sp4(0.9f),   m, g1);
  v = fma4(sp4(0.999f), v, g2);
  f32x4 r = rsq4(max4(v, 1e-30f));
  f32x4 t = m * sp4(cmsbr);
  p = fma4(-t, r, p);
}

// Layout (r6, proven): one wave per sample. lane = (g = lane>>4, u16 =
// lane&15); group g owns inner dims 6g..6g+5; lane owns j/c quad
// {4u16..4u16+3}. Reduces: allred16q (2 DS each). y cross-group combine:
// xor16 swz + shfl_xor(32). Zero barriers in the step loop.
// r9 change: b1 bias injection via masked-fma (mask in {1.0,0.0} computed
// once) — 12 fma/step instead of 12 cndmask+add. fmaf(b,1,x)==x+b and
// fmaf(b,0,x)==x+(+/-0) == lineage's x+0.0f (sign-dead post-relu).
__global__ __launch_bounds__(256, 2) void adapt_kernel(
    const int* __restrict__ seqs,       // [BATCH][32]
    const float* __restrict__ etab,     // [64][64]
    const float* __restrict__ mlp_w1,   // [64][24]
    const float* __restrict__ mlp_b1,   // [24]
    const float* __restrict__ mlp_w2,   // [24][64]
    const float* __restrict__ mlp_b2,   // [64]
    const float* __restrict__ out_w,    // [64][64]
    const float* __restrict__ out_b,    // [64]
    float* __restrict__ out)            // [BATCH][64]
{
  __shared__ __align__(16) float hqv[4][64];
  const int t    = threadIdx.x;        // 0..255
  const int wv   = t >> 6;             // wave in block = sample slot
  const int lane = t & 63;
  const int g    = lane >> 4;          // 0..3 (dim group)
  const int u16  = lane & 15;          // 0..15 (j/c quad index)
  const int s    = blockIdx.x * 4 + wv;
  const int off  = 6 * g;              // first inner dim of this group's 6

  // Tokens are wave-uniform: uniform (scalar) loads.
  const int* __restrict__ srow = seqs + s * SEQN + 14;

  // state: lane owns w1[4u16+sl][off+m] and w2[off+m][4u16+sl], sl=0..3
  f32x4 w1q[6], m1q[6], v1q[6], w2q[6], m2q[6], v2q[6];
  #pragma unroll
  for (int m = 0; m < 6; ++m) {
    f32x4 a;
    a.x = mlp_w1[(4 * u16 + 0) * INNER + off + m];
    a.y = mlp_w1[(4 * u16 + 1) * INNER + off + m];
    a.z = mlp_w1[(4 * u16 + 2) * INNER + off + m];
    a.w = mlp_w1[(4 * u16 + 3) * INNER + off + m];
    w1q[m] = a;
    w2q[m] = *(const f32x4*)&mlp_w2[(off + m) * HID + 4 * u16];
    m1q[m] = sp4(0.f); v1q[m] = sp4(0.f); m2q[m] = sp4(0.f); v2q[m] = sp4(0.f);
  }
  // b1: owner == injector lane. Bias for dim i=6g+m sits at leaf j = i mod 12
  // = 6*(g&1)+m -> lane u16 = j>>2, slot j&3 (same formulas as r5/r6).
  f32x4 b1q = sp4(0.f);
  if (!(g & 1)) {
    if (u16 == 0) { b1q.x = mlp_b1[off + 0]; b1q.y = mlp_b1[off + 1];
                    b1q.z = mlp_b1[off + 2]; b1q.w = mlp_b1[off + 3]; }
    else if (u16 == 1) { b1q.x = mlp_b1[off + 4]; b1q.y = mlp_b1[off + 5]; }
  } else {
    if (u16 == 1) { b1q.z = mlp_b1[off + 0]; b1q.w = mlp_b1[off + 1]; }
    else if (u16 == 2) { b1q.x = mlp_b1[off + 2]; b1q.y = mlp_b1[off + 3];
                         b1q.z = mlp_b1[off + 4]; b1q.w = mlp_b1[off + 5]; }
  }
  f32x4 mb1 = sp4(0.f), vb1 = sp4(0.f);
  // b2: every lane maintains b2[4u16..4u16+3] redundantly (same bits in all
  // groups). Seeded into the y chain only in group 0.
  f32x4 b2q = *(const f32x4*)&mlp_b2[4 * u16];
  f32x4 mb2 = sp4(0.f), vb2 = sp4(0.f);

  const bool ge0 = !(g & 1) && (u16 == 0);
  const bool ge1 = !(g & 1) && (u16 == 1);
  const bool go1 =  (g & 1) && (u16 == 1);
  const bool go2 =  (g & 1) && (u16 == 2);
  const bool g0a = (g == 0);
  // float masks for the masked-fma bias injection (computed once)
  const float fge0 = ge0 ? 1.f : 0.f;
  const float fge1 = ge1 ? 1.f : 0.f;
  const float fgo1 = go1 ? 1.f : 0.f;
  const float fgo2 = go2 ? 1.f : 0.f;

  // first k,v rows, quad layout (dwordx4 from L1/L2-resident etab)
  const f32x4* e4 = (const f32x4*)etab;
  f32x4 kp = e4[srow[0] * 16 + u16];
  f32x4 vp = e4[srow[1] * 16 + u16];

  #pragma unroll 2
  for (int st = 0; st < 8; ++st) {
    const float cmsbr = CMSBR[st];

    // forward: z_i = allred(k_j * w1[j][i]) + b1 at leaf (i mod 12).
    // Injection by masked-fma: identical bits to the cndmask+add lineage.
    f32x4 pz[6];
    #pragma unroll
    for (int m = 0; m < 6; ++m) pz[m] = kp * w1q[m];
    pz[0].x = fmaf(b1q.x, fge0, pz[0].x);  pz[0].z = fmaf(b1q.z, fgo1, pz[0].z);
    pz[1].y = fmaf(b1q.y, fge0, pz[1].y);  pz[1].w = fmaf(b1q.w, fgo1, pz[1].w);
    pz[2].z = fmaf(b1q.z, fge0, pz[2].z);  pz[2].x = fmaf(b1q.x, fgo2, pz[2].x);
    pz[3].w = fmaf(b1q.w, fge0, pz[3].w);  pz[3].y = fmaf(b1q.y, fgo2, pz[3].y);
    pz[4].x = fmaf(b1q.x, fge1, pz[4].x);  pz[4].z = fmaf(b1q.z, fgo2, pz[4].z);
    pz[5].y = fmaf(b1q.y, fge1, pz[5].y);  pz[5].w = fmaf(b1q.w, fgo2, pz[5].w);
    float a_[6];
    #pragma unroll
    for (int m = 0; m < 6; ++m) a_[m] = allred16q(pz[m]);
    #pragma unroll
    for (int m = 0; m < 6; ++m) a_[m] = fmaxf(a_[m], 0.f);

    // y chain over this group's 6 dims (seeded b2 in group 0 only)
    f32x4 yq;
    yq.x = g0a ? b2q.x : 0.f; yq.y = g0a ? b2q.y : 0.f;
    yq.z = g0a ? b2q.z : 0.f; yq.w = g0a ? b2q.w : 0.f;
    #pragma unroll
    for (int m = 0; m < 6; ++m) yq = fma4(sp4(a_[m]), w2q[m], yq);
    // combine: g-bit0 via xor16 swizzle, g-bit1 via shfl_xor(32)
    { f32x4 e; e.x = swz<0x401F>(yq.x); e.y = swz<0x401F>(yq.y);
               e.z = swz<0x401F>(yq.z); e.w = swz<0x401F>(yq.w);
      yq = yq + e; }
    { f32x4 e; e.x = __shfl_xor(yq.x, 32); e.y = __shfl_xor(yq.y, 32);
               e.z = __shfl_xor(yq.z, 32); e.w = __shfl_xor(yq.w, 32);
      yq = yq + e; }
    f32x4 dyq = (yq - vp) * sp4(0.03125f);   // 2/64

    // prefetch next step's k,v (st=7 harmlessly loads q row twice)
    int pp1 = 2 * st + 2; pp1 = pp1 < 16 ? pp1 : 16;
    int pp2 = 2 * st + 3; pp2 = pp2 < 16 ? pp2 : 16;
    f32x4 kn = e4[srow[pp1] * 16 + u16];
    f32x4 vn = e4[srow[pp2] * 16 + u16];

    // backward: dz_i = (z_i>0) * allred(w2[i][c]*dy_c)
    float dz[6];
    #pragma unroll
    for (int m = 0; m < 6; ++m) dz[m] = allred16q(w2q[m] * dyq);
    #pragma unroll
    for (int m = 0; m < 6; ++m) dz[m] = (a_[m] > 0.f) ? dz[m] : 0.f;

    // Adam step st+1 — w1/b1 first (gate next forward), then w2/b2
    // (unroll-2 lets the scheduler overlap these with the next forward).
    f32x4 k01  = kp * sp4(0.1f);
    f32x4 ksq  = (sp4(0.001f) * kp) * kp;
    f32x4 dy01 = dyq * sp4(0.1f);
    f32x4 dysq = (sp4(0.001f) * dyq) * dyq;
    #pragma unroll
    for (int m = 0; m < 6; ++m) {
      float dzs = dz[m] * dz[m];
      adam_q(w1q[m], m1q[m], v1q[m], k01 * sp4(dz[m]), ksq * sp4(dzs), cmsbr);
    }
    // b1 grads: owner slots gather their dz; non-owner slots get garbage that
    // is never read (lineage-sanctioned)
    {
      float gg0 = ge0 ? dz[0] : ge1 ? dz[4] : dz[2];
      float gg1 = ge0 ? dz[1] : ge1 ? dz[5] : dz[3];
      float gg2 = go1 ? dz[0] : ge0 ? dz[2] : dz[4];
      float gg3 = go1 ? dz[1] : ge0 ? dz[3] : dz[5];
      f32x4 g1b; g1b.x = 0.1f * gg0; g1b.y = 0.1f * gg1;
                 g1b.z = 0.1f * gg2; g1b.w = 0.1f * gg3;
      f32x4 g2b; g2b.x = 0.001f * (gg0 * gg0); g2b.y = 0.001f * (gg1 * gg1);
                 g2b.z = 0.001f * (gg2 * gg2); g2b.w = 0.001f * (gg3 * gg3);
      adam_q(b1q, mb1, vb1, g1b, g2b, cmsbr);
    }
    #pragma unroll
    for (int m = 0; m < 6; ++m) {
      float as = a_[m] * a_[m];
      adam_q(w2q[m], m2q[m], v2q[m], dy01 * sp4(a_[m]), dysq * sp4(as), cmsbr);
    }
    // b2: all lanes, redundant across groups (identical bits)
    adam_q(b2q, mb2, vb2, dy01, dysq, cmsbr);

    kp = kn; vp = vn;
  }

  // final forward with q (kp holds q row after last prefetch)
  {
    f32x4 pz[6];
    #pragma unroll
    for (int m = 0; m < 6; ++m) pz[m] = kp * w1q[m];
    pz[0].x = fmaf(b1q.x, fge0, pz[0].x);  pz[0].z = fmaf(b1q.z, fgo1, pz[0].z);
    pz[1].y = fmaf(b1q.y, fge0, pz[1].y);  pz[1].w = fmaf(b1q.w, fgo1, pz[1].w);
    pz[2].z = fmaf(b1q.z, fge0, pz[2].z);  pz[2].x = fmaf(b1q.x, fgo2, pz[2].x);
    pz[3].w = fmaf(b1q.w, fge0, pz[3].w);  pz[3].y = fmaf(b1q.y, fgo2, pz[3].y);
    pz[4].x = fmaf(b1q.x, fge1, pz[4].x);  pz[4].z = fmaf(b1q.z, fgo2, pz[4].z);
    pz[5].y = fmaf(b1q.y, fge1, pz[5].y);  pz[5].w = fmaf(b1q.w, fgo2, pz[5].w);
    float aq[6];
    #pragma unroll
    for (int m = 0; m < 6; ++m) aq[m] = fmaxf(allred16q(pz[m]), 0.f);
    f32x4 hq;
    hq.x = g0a ? b2q.x : 0.f; hq.y = g0a ? b2q.y : 0.f;
    hq.z = g0a ? b2q.z : 0.f; hq.w = g0a ? b2q.w : 0.f;
    #pragma unroll
    for (int m = 0; m < 6; ++m) hq = fma4(sp4(aq[m]), w2q[m], hq);
    { f32x4 e; e.x = swz<0x401F>(hq.x); e.y = swz<0x401F>(hq.y);
               e.z = swz<0x401F>(hq.z); e.w = swz<0x401F>(hq.w);
      hq = hq + e; }
    { f32x4 e; e.x = __shfl_xor(hq.x, 32); e.y = __shfl_xor(hq.y, 32);
               e.z = __shfl_xor(hq.z, 32); e.w = __shfl_xor(hq.w, 32);
      hq = hq + e; }
    if (g0a) ((f32x4*)hqv[wv])[u16] = hq;   // hqv[wv][4u16+sl] = hq_j
  }
  __syncthreads();   // once per kernel: publish hqv

  {
    // out[s][c] = sum_j hq[j] * out_w[j][c] + out_b[c]   (lane = c, all 64)
    float acc = out_b[lane];
    const f32x4* hv = (const f32x4*)hqv[wv];
    #pragma unroll
    for (int j4 = 0; j4 < 16; ++j4) {
      f32x4 h4 = hv[j4];
      acc = fmaf(h4.x, out_w[(4 * j4 + 0) * 64 + lane], acc);
      acc = fmaf(h4.y, out_w[(4 * j4 + 1) * 64 + lane], acc);
      acc = fmaf(h4.z, out_w[(4 * j4 + 2) * 64 + lane], acc);
      acc = fmaf(h4.w, out_w[(4 * j4 + 3) * 64 + lane], acc);
    }
    out[(size_t)s * 64 + lane] = acc;
  }
}

extern "C" void kernel_launch(void* const* d_in, const int* in_sizes, int n_in,
                              void* d_out, int out_size, void* d_ws, size_t ws_size,
                              hipStream_t stream) {
  const int*   seqs   = (const int*)d_in[0];
  const float* embed  = (const float*)d_in[1];
  const float* ff_w1  = (const float*)d_in[2];
  const float* ff_b1  = (const float*)d_in[3];
  const float* ff_w2  = (const float*)d_in[4];
  const float* ff_b2  = (const float*)d_in[5];
  const float* ln_g   = (const float*)d_in[6];
  const float* ln_b   = (const float*)d_in[7];
  const float* mlp_w1 = (const float*)d_in[8];
  const float* mlp_b1 = (const float*)d_in[9];
  const float* mlp_w2 = (const float*)d_in[10];
  const float* mlp_b2 = (const float*)d_in[11];
  const float* out_w  = (const float*)d_in[12];
  const float* out_b  = (const float*)d_in[13];

  float* etab = (float*)d_ws;   // 64*64 f32 = 16 KB

  build_table<<<64, 128, 0, stream>>>(
      embed, ff_w1, ff_b1, ff_w2, ff_b2, ln_g, ln_b, etab);
  adapt_kernel<<<BATCHN / 4, 256, 0, stream>>>(
      seqs, etab, mlp_w1, mlp_b1, mlp_w2, mlp_b2, out_w, out_b,
      (float*)d_out);
}

// Round 10
// 169.873 us; speedup vs baseline: 1.0290x; 1.0026x over previous
//
#include <hip/hip_runtime.h>
#include <hip/hip_bf16.h>
#include <math.h>

// Problem constants
#define HID   64
#define VOCABN 64
#define INNER 24
#define SEQN  32
#define CAPN  8
#define NPOS  17
#define BATCHN 8192

typedef float f32x4 __attribute__((ext_vector_type(4)));

// f32x4 helpers. (r2: packing saves issue slots only, not fp32 ALU cycles.
// r8: kernel is VALU-THROUGHPUT-bound — DS butterfly ops are hidden/free.
// r9: allocator sits on a spill cliff at ~184 persistent regs/lane; keep
// live ranges tight. 56 rsq/step at quarter-rate = ~17% of the VALU budget.)
static __device__ __forceinline__ f32x4 sp4(float x) { return (f32x4){x, x, x, x}; }
static __device__ __forceinline__ f32x4 fma4(f32x4 a, f32x4 b, f32x4 c) {
  f32x4 r; r.x = fmaf(a.x, b.x, c.x); r.y = fmaf(a.y, b.y, c.y);
           r.z = fmaf(a.z, b.z, c.z); r.w = fmaf(a.w, b.w, c.w); return r;
}
static __device__ __forceinline__ f32x4 max4(f32x4 a, float b) {
  f32x4 r; r.x = fmaxf(a.x, b); r.y = fmaxf(a.y, b);
           r.z = fmaxf(a.z, b); r.w = fmaxf(a.w, b); return r;
}
static __device__ __forceinline__ f32x4 rsq4(f32x4 a) {
  f32x4 r; r.x = __builtin_amdgcn_rsqf(a.x); r.y = __builtin_amdgcn_rsqf(a.y);
           r.z = __builtin_amdgcn_rsqf(a.z); r.w = __builtin_amdgcn_rsqf(a.w); return r;
}

// Per-step Adam prefactor (double-precision offline):
//   cmsbr[t] = LR * sqrt(1 - B2^(t+1)) / (1 - B1^(t+1)),  t = 0..7
static __device__ const float CMSBR[8] = {
  0.01581139f, 0.01176584f, 0.01010053f, 0.00918844f,
  0.00862495f, 0.00825540f, 0.00800653f, 0.00783856f
};

// ds_swizzle pattern must be an integer-constant-expression at the builtin
// call site (r4 compile failure) -> template parameter.
template <int PAT>
static __device__ __forceinline__ float swz(float x) {
  return __int_as_float(__builtin_amdgcn_ds_swizzle(__float_as_int(x), PAT));
}

// ---------- quad all-reduce: 64 leaves j = 4*u16 + slot, u16 = lane&15 ----------
// Bit-exact lineage tree: bits 0,1 in-register; bit2 = lane^1 (DPP);
// bit3 = lane^2 (DPP); bit4 = lane^4 (swz); bit5 = lane^8 (swz).
// r8 lesson: the 2 DS ops/reduce are FREE (hidden); permlane (VALU) was
// 16 us slower. This is the proven r6 form.
__device__ __forceinline__ float allred16q(f32x4 p) {
  float x = (p.x + p.y) + (p.z + p.w);   // j-bits 0,1
  int y;
  y = __builtin_amdgcn_update_dpp(__float_as_int(x), __float_as_int(x),
                                  0xB1, 0xF, 0xF, false);   // u16^1 -> j-bit2
  x += __int_as_float(y);
  y = __builtin_amdgcn_update_dpp(__float_as_int(x), __float_as_int(x),
                                  0x4E, 0xF, 0xF, false);   // u16^2 -> j-bit3
  x += __int_as_float(y);
  x += swz<0x101F>(x);                                      // u16^4 -> j-bit4
  x += swz<0x201F>(x);                                      // u16^8 -> j-bit5
  return x;
}

// ---------- Kernel 1: per-token encoder table (verbatim, passing) ----------
__global__ __launch_bounds__(128) void build_table(
    const float* __restrict__ embed,    // [64][64]
    const float* __restrict__ ff_w1,    // [64][128]
    const float* __restrict__ ff_b1,    // [128]
    const float* __restrict__ ff_w2,    // [128][64]
    const float* __restrict__ ff_b2,    // [64]
    const float* __restrict__ ln_g,     // [64]
    const float* __restrict__ ln_b,     // [64]
    float* __restrict__ etab)           // [64][64]
{
  __shared__ float h[64];
  __shared__ float A1[128];
  __shared__ float xs[64];
  const int r = blockIdx.x;
  const int t = threadIdx.x;

  if (t < 64) h[t] = embed[r * 64 + t];
  __syncthreads();

  {
    float acc = ff_b1[t];
    #pragma unroll 8
    for (int k = 0; k < 64; ++k)
      acc = fmaf(h[k], ff_w1[k * 128 + t], acc);
    A1[t] = fmaxf(acc, 0.f);
  }
  __syncthreads();

  if (t < 64) {
    float acc = ff_b2[t];
    #pragma unroll 8
    for (int k = 0; k < 128; ++k)
      acc = fmaf(A1[k], ff_w2[k * 64 + t], acc);
    xs[t] = acc + h[t];
  }
  __syncthreads();

  if (t < 64) {
    float s1 = 0.f;
    if (t < 4)
      for (int j = 0; j < 16; ++j) s1 += xs[t + 4 * j];
    s1 += __shfl_xor(s1, 1);
    s1 += __shfl_xor(s1, 2);
    s1 = __shfl(s1, 0);
    float mu = s1 * 0.015625f;

    float s2 = 0.f;
    if (t < 4)
      for (int j = 0; j < 16; ++j) {
        float d = xs[t + 4 * j] - mu;
        s2 = fmaf(d, d, s2);
      }
    s2 += __shfl_xor(s2, 1);
    s2 += __shfl_xor(s2, 2);
    s2 = __shfl(s2, 0);
    float var = s2 * 0.015625f;
    float rs  = rsqrtf(var + 1e-5f);

    etab[r * 64 + t] = fmaf((xs[t] - mu) * rs, ln_g[t], ln_b[t]);
  }
}

// ---------- Kernel 2: 1-wave-per-sample, quad layout, 8-step Adam ----------
// Bit-exact per component with the r9-lineage scalar adam_upd.
__device__ __forceinline__ void adam_q(f32x4& p, f32x4& m, f32x4& v,
                                       f32x4 g1, f32x4 g2, float cmsbr) {
  m = fma4(sp4(0.9f),   m, g1);
  v = fma4(sp4(0.999f), v, g2);
  f32x4 r = rsq4(max4(v, 1e-30f));
  f32x4 t = m * sp4(cmsbr);
  p = fma4(-t, r, p);
}

// Layout (r6, proven 95.0 us): one wave per sample. lane = (g = lane>>4,
// u16 = lane&15); group g owns inner dims 6g..6g+5; lane owns j/c quad
// {4u16..4u16+3}. Reduces: allred16q (2 hidden DS each). y cross-group
// combine: xor16 swz + shfl_xor(32). Zero barriers in the step loop.
// r10 changes vs r9: bias injection back to cndmask (masked-fma grew live
// ranges -> scratch spill, FETCH/WRITE +3MB); kn/vn prefetch moved AFTER
// the backward reduce (L1-resident loads hide under the ~1200cy Adam block;
// frees 8 VGPRs across fwd+y+bwd to stay under the spill cliff).
__global__ __launch_bounds__(256, 2) void adapt_kernel(
    const int* __restrict__ seqs,       // [BATCH][32]
    const float* __restrict__ etab,     // [64][64]
    const float* __restrict__ mlp_w1,   // [64][24]
    const float* __restrict__ mlp_b1,   // [24]
    const float* __restrict__ mlp_w2,   // [24][64]
    const float* __restrict__ mlp_b2,   // [64]
    const float* __restrict__ out_w,    // [64][64]
    const float* __restrict__ out_b,    // [64]
    float* __restrict__ out)            // [BATCH][64]
{
  __shared__ __align__(16) float hqv[4][64];
  const int t    = threadIdx.x;        // 0..255
  const int wv   = t >> 6;             // wave in block = sample slot
  const int lane = t & 63;
  const int g    = lane >> 4;          // 0..3 (dim group)
  const int u16  = lane & 15;          // 0..15 (j/c quad index)
  const int s    = blockIdx.x * 4 + wv;
  const int off  = 6 * g;              // first inner dim of this group's 6

  // Tokens are wave-uniform: uniform (scalar) loads.
  const int* __restrict__ srow = seqs + s * SEQN + 14;

  // state: lane owns w1[4u16+sl][off+m] and w2[off+m][4u16+sl], sl=0..3
  f32x4 w1q[6], m1q[6], v1q[6], w2q[6], m2q[6], v2q[6];
  #pragma unroll
  for (int m = 0; m < 6; ++m) {
    f32x4 a;
    a.x = mlp_w1[(4 * u16 + 0) * INNER + off + m];
    a.y = mlp_w1[(4 * u16 + 1) * INNER + off + m];
    a.z = mlp_w1[(4 * u16 + 2) * INNER + off + m];
    a.w = mlp_w1[(4 * u16 + 3) * INNER + off + m];
    w1q[m] = a;
    w2q[m] = *(const f32x4*)&mlp_w2[(off + m) * HID + 4 * u16];
    m1q[m] = sp4(0.f); v1q[m] = sp4(0.f); m2q[m] = sp4(0.f); v2q[m] = sp4(0.f);
  }
  // b1: owner == injector lane. Bias for dim i=6g+m sits at leaf j = i mod 12
  // = 6*(g&1)+m -> lane u16 = j>>2, slot j&3 (same formulas as r5/r6).
  f32x4 b1q = sp4(0.f);
  if (!(g & 1)) {
    if (u16 == 0) { b1q.x = mlp_b1[off + 0]; b1q.y = mlp_b1[off + 1];
                    b1q.z = mlp_b1[off + 2]; b1q.w = mlp_b1[off + 3]; }
    else if (u16 == 1) { b1q.x = mlp_b1[off + 4]; b1q.y = mlp_b1[off + 5]; }
  } else {
    if (u16 == 1) { b1q.z = mlp_b1[off + 0]; b1q.w = mlp_b1[off + 1]; }
    else if (u16 == 2) { b1q.x = mlp_b1[off + 2]; b1q.y = mlp_b1[off + 3];
                         b1q.z = mlp_b1[off + 4]; b1q.w = mlp_b1[off + 5]; }
  }
  f32x4 mb1 = sp4(0.f), vb1 = sp4(0.f);
  // b2: every lane maintains b2[4u16..4u16+3] redundantly (same bits in all
  // groups). Seeded into the y chain only in group 0.
  f32x4 b2q = *(const f32x4*)&mlp_b2[4 * u16];
  f32x4 mb2 = sp4(0.f), vb2 = sp4(0.f);

  const bool ge0 = !(g & 1) && (u16 == 0);
  const bool ge1 = !(g & 1) && (u16 == 1);
  const bool go1 =  (g & 1) && (u16 == 1);
  const bool go2 =  (g & 1) && (u16 == 2);
  const bool g0a = (g == 0);

  // first k,v rows, quad layout (dwordx4 from L1-resident etab — 16 KB)
  const f32x4* e4 = (const f32x4*)etab;
  f32x4 kp = e4[srow[0] * 16 + u16];
  f32x4 vp = e4[srow[1] * 16 + u16];

  #pragma unroll 2
  for (int st = 0; st < 8; ++st) {
    const float cmsbr = CMSBR[st];

    // forward: z_i = allred(k_j * w1[j][i]) + b1 at leaf (i mod 12).
    f32x4 pz[6];
    #pragma unroll
    for (int m = 0; m < 6; ++m) pz[m] = kp * w1q[m];
    pz[0].x += ge0 ? b1q.x : 0.f;  pz[0].z += go1 ? b1q.z : 0.f;
    pz[1].y += ge0 ? b1q.y : 0.f;  pz[1].w += go1 ? b1q.w : 0.f;
    pz[2].z += ge0 ? b1q.z : 0.f;  pz[2].x += go2 ? b1q.x : 0.f;
    pz[3].w += ge0 ? b1q.w : 0.f;  pz[3].y += go2 ? b1q.y : 0.f;
    pz[4].x += ge1 ? b1q.x : 0.f;  pz[4].z += go2 ? b1q.z : 0.f;
    pz[5].y += ge1 ? b1q.y : 0.f;  pz[5].w += go2 ? b1q.w : 0.f;
    float a_[6];
    #pragma unroll
    for (int m = 0; m < 6; ++m) a_[m] = allred16q(pz[m]);
    #pragma unroll
    for (int m = 0; m < 6; ++m) a_[m] = fmaxf(a_[m], 0.f);

    // y chain over this group's 6 dims (seeded b2 in group 0 only)
    f32x4 yq;
    yq.x = g0a ? b2q.x : 0.f; yq.y = g0a ? b2q.y : 0.f;
    yq.z = g0a ? b2q.z : 0.f; yq.w = g0a ? b2q.w : 0.f;
    #pragma unroll
    for (int m = 0; m < 6; ++m) yq = fma4(sp4(a_[m]), w2q[m], yq);
    // combine: g-bit0 via xor16 swizzle, g-bit1 via shfl_xor(32)
    { f32x4 e; e.x = swz<0x401F>(yq.x); e.y = swz<0x401F>(yq.y);
               e.z = swz<0x401F>(yq.z); e.w = swz<0x401F>(yq.w);
      yq = yq + e; }
    { f32x4 e; e.x = __shfl_xor(yq.x, 32); e.y = __shfl_xor(yq.y, 32);
               e.z = __shfl_xor(yq.z, 32); e.w = __shfl_xor(yq.w, 32);
      yq = yq + e; }
    f32x4 dyq = (yq - vp) * sp4(0.03125f);   // 2/64

    // backward: dz_i = (z_i>0) * allred(w2[i][c]*dy_c)
    float dz[6];
    #pragma unroll
    for (int m = 0; m < 6; ++m) dz[m] = allred16q(w2q[m] * dyq);
    #pragma unroll
    for (int m = 0; m < 6; ++m) dz[m] = (a_[m] > 0.f) ? dz[m] : 0.f;

    // prefetch next step's k,v (L1-hit; hides under the Adam block below;
    // issued late so kn/vn are not live across fwd+y+bwd — r10 live-range fix)
    int pp1 = 2 * st + 2; pp1 = pp1 < 16 ? pp1 : 16;
    int pp2 = 2 * st + 3; pp2 = pp2 < 16 ? pp2 : 16;
    f32x4 kn = e4[srow[pp1] * 16 + u16];
    f32x4 vn = e4[srow[pp2] * 16 + u16];

    // Adam step st+1 — w1/b1 first (gate next forward), then w2/b2
    // (unroll-2 lets the scheduler overlap these with the next forward).
    f32x4 k01  = kp * sp4(0.1f);
    f32x4 ksq  = (sp4(0.001f) * kp) * kp;
    f32x4 dy01 = dyq * sp4(0.1f);
    f32x4 dysq = (sp4(0.001f) * dyq) * dyq;
    #pragma unroll
    for (int m = 0; m < 6; ++m) {
      float dzs = dz[m] * dz[m];
      adam_q(w1q[m], m1q[m], v1q[m], k01 * sp4(dz[m]), ksq * sp4(dzs), cmsbr);
    }
    // b1 grads: owner slots gather their dz; non-owner slots get garbage that
    // is never read (lineage-sanctioned)
    {
      float gg0 = ge0 ? dz[0] : ge1 ? dz[4] : dz[2];
      float gg1 = ge0 ? dz[1] : ge1 ? dz[5] : dz[3];
      float gg2 = go1 ? dz[0] : ge0 ? dz[2] : dz[4];
      float gg3 = go1 ? dz[1] : ge0 ? dz[3] : dz[5];
      f32x4 g1b; g1b.x = 0.1f * gg0; g1b.y = 0.1f * gg1;
                 g1b.z = 0.1f * gg2; g1b.w = 0.1f * gg3;
      f32x4 g2b; g2b.x = 0.001f * (gg0 * gg0); g2b.y = 0.001f * (gg1 * gg1);
                 g2b.z = 0.001f * (gg2 * gg2); g2b.w = 0.001f * (gg3 * gg3);
      adam_q(b1q, mb1, vb1, g1b, g2b, cmsbr);
    }
    #pragma unroll
    for (int m = 0; m < 6; ++m) {
      float as = a_[m] * a_[m];
      adam_q(w2q[m], m2q[m], v2q[m], dy01 * sp4(a_[m]), dysq * sp4(as), cmsbr);
    }
    // b2: all lanes, redundant across groups (identical bits)
    adam_q(b2q, mb2, vb2, dy01, dysq, cmsbr);

    kp = kn; vp = vn;
  }

  // final forward with q (kp holds q row after last prefetch)
  {
    f32x4 pz[6];
    #pragma unroll
    for (int m = 0; m < 6; ++m) pz[m] = kp * w1q[m];
    pz[0].x += ge0 ? b1q.x : 0.f;  pz[0].z += go1 ? b1q.z : 0.f;
    pz[1].y += ge0 ? b1q.y : 0.f;  pz[1].w += go1 ? b1q.w : 0.f;
    pz[2].z += ge0 ? b1q.z : 0.f;  pz[2].x += go2 ? b1q.x : 0.f;
    pz[3].w += ge0 ? b1q.w : 0.f;  pz[3].y += go2 ? b1q.y : 0.f;
    pz[4].x += ge1 ? b1q.x : 0.f;  pz[4].z += go2 ? b1q.z : 0.f;
    pz[5].y += ge1 ? b1q.y : 0.f;  pz[5].w += go2 ? b1q.w : 0.f;
    float aq[6];
    #pragma unroll
    for (int m = 0; m < 6; ++m) aq[m] = fmaxf(allred16q(pz[m]), 0.f);
    f32x4 hq;
    hq.x = g0a ? b2q.x : 0.f; hq.y = g0a ? b2q.y : 0.f;
    hq.z = g0a ? b2q.z : 0.f; hq.w = g0a ? b2q.w : 0.f;
    #pragma unroll
    for (int m = 0; m < 6; ++m) hq = fma4(sp4(aq[m]), w2q[m], hq);
    { f32x4 e; e.x = swz<0x401F>(hq.x); e.y = swz<0x401F>(hq.y);
               e.z = swz<0x401F>(hq.z); e.w = swz<0x401F>(hq.w);
      hq = hq + e; }
    { f32x4 e; e.x = __shfl_xor(hq.x, 32); e.y = __shfl_xor(hq.y, 32);
               e.z = __shfl_xor(hq.z, 32); e.w = __shfl_xor(hq.w, 32);
      hq = hq + e; }
    if (g0a) ((f32x4*)hqv[wv])[u16] = hq;   // hqv[wv][4u16+sl] = hq_j
  }
  __syncthreads();   // once per kernel: publish hqv

  {
    // out[s][c] = sum_j hq[j] * out_w[j][c] + out_b[c]   (lane = c, all 64)
    float acc = out_b[lane];
    const f32x4* hv = (const f32x4*)hqv[wv];
    #pragma unroll
    for (int j4 = 0; j4 < 16; ++j4) {
      f32x4 h4 = hv[j4];
      acc = fmaf(h4.x, out_w[(4 * j4 + 0) * 64 + lane], acc);
      acc = fmaf(h4.y, out_w[(4 * j4 + 1) * 64 + lane], acc);
      acc = fmaf(h4.z, out_w[(4 * j4 + 2) * 64 + lane], acc);
      acc = fmaf(h4.w, out_w[(4 * j4 + 3) * 64 + lane], acc);
    }
    out[(size_t)s * 64 + lane] = acc;
  }
}

extern "C" void kernel_launch(void* const* d_in, const int* in_sizes, int n_in,
                              void* d_out, int out_size, void* d_ws, size_t ws_size,
                              hipStream_t stream) {
  const int*   seqs   = (const int*)d_in[0];
  const float* embed  = (const float*)d_in[1];
  const float* ff_w1  = (const float*)d_in[2];
  const float* ff_b1  = (const float*)d_in[3];
  const float* ff_w2  = (const float*)d_in[4];
  const float* ff_b2  = (const float*)d_in[5];
  const float* ln_g   = (const float*)d_in[6];
  const float* ln_b   = (const float*)d_in[7];
  const float* mlp_w1 = (const float*)d_in[8];
  const float* mlp_b1 = (const float*)d_in[9];
  const float* mlp_w2 = (const float*)d_in[10];
  const float* mlp_b2 = (const float*)d_in[11];
  const float* out_w  = (const float*)d_in[12];
  const float* out_b  = (const float*)d_in[13];

  float* etab = (float*)d_ws;   // 64*64 f32 = 16 KB

  build_table<<<64, 128, 0, stream>>>(
      embed, ff_w1, ff_b1, ff_w2, ff_b2, ln_g, ln_b, etab);
  adapt_kernel<<<BATCHN / 4, 256, 0, stream>>>(
      seqs, etab, mlp_w1, mlp_b1, mlp_w2, mlp_b2, out_w, out_b,
      (float*)d_out);
}